// Round 2
// baseline (408.362 us; speedup 1.0000x reference)
//
#include <hip/hip_runtime.h>
#include <hip/hip_bf16.h>

// Problem constants (B,H,W,C) = (4,56,56,256), nh=8, K=7, lr=4, hd=32
#define BD 4
#define HD_ 56
#define WD 56
#define CD 256
#define NH 8
#define KW 7
#define LR 4
#define HDIM 32
#define MB (HD_*WD)              // 3136 rows per batch
#define QK_PER_B (HD_*WD*32)     // 100352  (q/k per-batch floats)
#define V_PER_B  (HD_*WD*256)    // 802816

// ---------------- pack [Wq|Wk|Wv] into 256x320 + packed bias ----------------
__global__ __launch_bounds__(256) void pack_w(
    const float* __restrict__ Wq, const float* __restrict__ Wk,
    const float* __restrict__ Wv, const float* __restrict__ bq,
    const float* __restrict__ bk, const float* __restrict__ bv,
    float* __restrict__ Wpk, float* __restrict__ pb)
{
    int idx = blockIdx.x * 256 + threadIdx.x;
    if (idx < 256 * 320) {
        int k = idx / 320, n = idx % 320;
        float v;
        if (n < 32)       v = Wq[k * 32 + n];
        else if (n < 64)  v = Wk[k * 32 + (n - 32)];
        else              v = Wv[k * 256 + (n - 64)];
        Wpk[idx] = v;
    }
    if (idx < 320) {
        pb[idx] = (idx < 32) ? bq[idx] : (idx < 64) ? bk[idx - 32] : bv[idx - 64];
    }
}

// ---------------- tiled SGEMM: QKV projection (one batch) ----------------
// C[m,n] = X[m,:] @ Wpk[:,n] + pb[n];  M=3136, K=256, N=320
// epilogue scatters into Qb (w32), Kb (w32), Vb (w256)
__global__ __launch_bounds__(256) void sgemm_qkv(
    const float* __restrict__ X, const float* __restrict__ Wpk,
    const float* __restrict__ pb, float* __restrict__ Qb,
    float* __restrict__ Kb, float* __restrict__ Vb)
{
    __shared__ float As[64][20];   // stride 20 floats (16B-aligned rows)
    __shared__ float Bs[16][68];
    const int t  = threadIdx.x;
    const int tx = t & 15, ty = t >> 4;
    const int m0 = blockIdx.y * 64;
    const int n0 = blockIdx.x * 64;

    const int ar = t >> 2;          // 0..63
    const int ac = (t & 3) * 4;     // 0,4,8,12
    const int br = t >> 4;          // 0..15
    const int bc = (t & 15) * 4;    // 0..60

    float acc[4][4] = {};

    for (int k0 = 0; k0 < 256; k0 += 16) {
        float4 av = *(const float4*)&X[(m0 + ar) * 256 + k0 + ac];
        float4 bv = *(const float4*)&Wpk[(k0 + br) * 320 + n0 + bc];
        __syncthreads();
        *(float4*)&As[ar][ac] = av;
        *(float4*)&Bs[br][bc] = bv;
        __syncthreads();
#pragma unroll
        for (int kk = 0; kk < 16; ++kk) {
            float a0 = As[ty * 4 + 0][kk];
            float a1 = As[ty * 4 + 1][kk];
            float a2 = As[ty * 4 + 2][kk];
            float a3 = As[ty * 4 + 3][kk];
            float4 b = *(float4*)&Bs[kk][tx * 4];
            acc[0][0] += a0 * b.x; acc[0][1] += a0 * b.y; acc[0][2] += a0 * b.z; acc[0][3] += a0 * b.w;
            acc[1][0] += a1 * b.x; acc[1][1] += a1 * b.y; acc[1][2] += a1 * b.z; acc[1][3] += a1 * b.w;
            acc[2][0] += a2 * b.x; acc[2][1] += a2 * b.y; acc[2][2] += a2 * b.z; acc[2][3] += a2 * b.w;
            acc[3][0] += a3 * b.x; acc[3][1] += a3 * b.y; acc[3][2] += a3 * b.z; acc[3][3] += a3 * b.w;
        }
    }

#pragma unroll
    for (int ii = 0; ii < 4; ++ii) {
        int m = m0 + ty * 4 + ii;
#pragma unroll
        for (int jj = 0; jj < 4; ++jj) {
            int n = n0 + tx * 4 + jj;
            float v = acc[ii][jj] + pb[n];
            if (n < 32)       Qb[m * 32 + n] = v;
            else if (n < 64)  Kb[m * 32 + (n - 32)] = v;
            else              Vb[m * 256 + (n - 64)] = v;
        }
    }
}

// ---------------- NATTEN attention (one batch): one thread per (n,i,j) ------
// Writes att_b in (H,W,C) layout (channel block = head n).
__global__ __launch_bounds__(256) void natten_attn(
    const float* __restrict__ Qb, const float* __restrict__ Kb,
    const float* __restrict__ Vb, const float* __restrict__ rpb,
    float* __restrict__ Ab)
{
    int tid = blockIdx.x * 256 + threadIdx.x;   // 0..25087
    int j  = tid % WD;
    int t1 = tid / WD;
    int i  = t1 % HD_;
    int n  = t1 / HD_;                          // 0..7

    const float scale = 0.17677669529663687f;   // 32^-0.5
    int sh = min(max(i - 3, 0), HD_ - KW);
    int sw = min(max(j - 3, 0), WD - KW);

    // raw-reshape view: q[n,i,j,l] = Qb[n*12544 + i*224 + j*4 + l]
    float4 q = *(const float4*)&Qb[n * (HD_ * WD * LR) + i * (WD * LR) + j * LR];
    const float* kb = &Kb[n * (HD_ * WD * LR)];
    const float* rb = &rpb[n * 169];

    float s[49];
    float mx = -3.4e38f;
#pragma unroll
    for (int kh = 0; kh < KW; ++kh) {
        int ih = sh + kh;
        int bi = ih - i + 6;
#pragma unroll
        for (int kw = 0; kw < KW; ++kw) {
            int iw = sw + kw;
            float4 kv = *(const float4*)&kb[ih * (WD * LR) + iw * LR];
            float d = q.x * kv.x + q.y * kv.y + q.z * kv.z + q.w * kv.w;
            float sc = d * scale + rb[bi * 13 + (iw - j + 6)];
            s[kh * KW + kw] = sc;
            mx = fmaxf(mx, sc);
        }
    }
    float sum = 0.f;
#pragma unroll
    for (int p = 0; p < 49; ++p) { float e = __expf(s[p] - mx); s[p] = e; sum += e; }
    float inv = 1.0f / sum;

    float acc[32];
#pragma unroll
    for (int d = 0; d < 32; ++d) acc[d] = 0.f;

    const float* vb = &Vb[n * (HD_ * WD * HDIM)];
#pragma unroll
    for (int kh = 0; kh < KW; ++kh) {
        int ih = sh + kh;
#pragma unroll
        for (int kw = 0; kw < KW; ++kw) {
            float p = s[kh * KW + kw] * inv;
            const float* vp = &vb[ih * (WD * HDIM) + (sw + kw) * HDIM];
#pragma unroll
            for (int d4 = 0; d4 < 8; ++d4) {
                float4 vv = *(const float4*)&vp[d4 * 4];
                acc[d4 * 4 + 0] += p * vv.x;
                acc[d4 * 4 + 1] += p * vv.y;
                acc[d4 * 4 + 2] += p * vv.z;
                acc[d4 * 4 + 3] += p * vv.w;
            }
        }
    }

    float* op = &Ab[(i * WD + j) * CD + n * HDIM];
#pragma unroll
    for (int d4 = 0; d4 < 8; ++d4) {
        *(float4*)&op[d4 * 4] = make_float4(acc[d4 * 4 + 0], acc[d4 * 4 + 1],
                                            acc[d4 * 4 + 2], acc[d4 * 4 + 3]);
    }
}

// ---------------- tiled SGEMM: output projection (one batch) ----------------
// out[m,n] = A[m,:] @ Wp[:,n] + bp[n];  M=3136, K=256, N=256
__global__ __launch_bounds__(256) void sgemm_out(
    const float* __restrict__ A, const float* __restrict__ Wp,
    const float* __restrict__ bp, float* __restrict__ out)
{
    __shared__ float As[64][20];
    __shared__ float Bs[16][68];
    const int t  = threadIdx.x;
    const int tx = t & 15, ty = t >> 4;
    const int m0 = blockIdx.y * 64;
    const int n0 = blockIdx.x * 64;

    const int ar = t >> 2;
    const int ac = (t & 3) * 4;
    const int br = t >> 4;
    const int bc = (t & 15) * 4;

    float acc[4][4] = {};

    for (int k0 = 0; k0 < 256; k0 += 16) {
        float4 av = *(const float4*)&A[(m0 + ar) * 256 + k0 + ac];
        float4 bv = *(const float4*)&Wp[(k0 + br) * 256 + n0 + bc];
        __syncthreads();
        *(float4*)&As[ar][ac] = av;
        *(float4*)&Bs[br][bc] = bv;
        __syncthreads();
#pragma unroll
        for (int kk = 0; kk < 16; ++kk) {
            float a0 = As[ty * 4 + 0][kk];
            float a1 = As[ty * 4 + 1][kk];
            float a2 = As[ty * 4 + 2][kk];
            float a3 = As[ty * 4 + 3][kk];
            float4 b = *(float4*)&Bs[kk][tx * 4];
            acc[0][0] += a0 * b.x; acc[0][1] += a0 * b.y; acc[0][2] += a0 * b.z; acc[0][3] += a0 * b.w;
            acc[1][0] += a1 * b.x; acc[1][1] += a1 * b.y; acc[1][2] += a1 * b.z; acc[1][3] += a1 * b.w;
            acc[2][0] += a2 * b.x; acc[2][1] += a2 * b.y; acc[2][2] += a2 * b.z; acc[2][3] += a2 * b.w;
            acc[3][0] += a3 * b.x; acc[3][1] += a3 * b.y; acc[3][2] += a3 * b.z; acc[3][3] += a3 * b.w;
        }
    }

#pragma unroll
    for (int ii = 0; ii < 4; ++ii) {
        int m = m0 + ty * 4 + ii;
#pragma unroll
        for (int jj = 0; jj < 4; ++jj) {
            int n = n0 + tx * 4 + jj;
            out[m * 256 + n] = acc[ii][jj] + bp[n];
        }
    }
}

extern "C" void kernel_launch(void* const* d_in, const int* in_sizes, int n_in,
                              void* d_out, int out_size, void* d_ws, size_t ws_size,
                              hipStream_t stream) {
    const float* x   = (const float*)d_in[0];
    const float* Wq  = (const float*)d_in[1];
    const float* bq  = (const float*)d_in[2];
    const float* Wk  = (const float*)d_in[3];
    const float* bk  = (const float*)d_in[4];
    const float* Wv  = (const float*)d_in[5];
    const float* bv  = (const float*)d_in[6];
    const float* rpb = (const float*)d_in[7];
    const float* Wp  = (const float*)d_in[8];
    const float* bp  = (const float*)d_in[9];
    float* out = (float*)d_out;

    // workspace layout (floats) — per-batch tiling keeps footprint ~7.55 MB
    float* ws   = (float*)d_ws;
    float* Wpk  = ws;                    // 81920
    float* pb   = Wpk + 81920;           // 320
    float* Qb   = pb + 320;              // 100352
    float* Kb   = Qb + QK_PER_B;         // 100352
    float* Vb   = Kb + QK_PER_B;         // 802816
    float* Ab   = Vb + V_PER_B;          // 802816
    // total 1,888,576 floats = 7.55 MB

    pack_w<<<(256 * 320 + 255) / 256, 256, 0, stream>>>(Wq, Wk, Wv, bq, bk, bv, Wpk, pb);

    for (int b = 0; b < BD; ++b) {
        const float* xb = x + (size_t)b * MB * CD;
        float* outb = out + (size_t)b * MB * CD;

        dim3 gq(320 / 64, MB / 64);
        sgemm_qkv<<<gq, 256, 0, stream>>>(xb, Wpk, pb, Qb, Kb, Vb);

        natten_attn<<<(NH * MB) / 256, 256, 0, stream>>>(Qb, Kb, Vb, rpb, Ab);

        dim3 go(256 / 64, MB / 64);
        sgemm_out<<<go, 256, 0, stream>>>(Ab, Wp, bp, outb);
    }
}

// Round 3
// 257.314 us; speedup vs baseline: 1.5870x; 1.5870x over previous
//
#include <hip/hip_runtime.h>
#include <hip/hip_bf16.h>

// Problem constants (B,H,W,C) = (4,56,56,256), nh=8, K=7, lr=4, hd=32
#define BD 4
#define HD_ 56
#define WD 56
#define CD 256
#define NH 8
#define KW 7
#define LR 4
#define HDIM 32
#define MB (HD_*WD)              // 3136 rows per batch
#define QK_PER_B (HD_*WD*32)     // 100352  (q/k per-batch floats)
#define V_PER_B  (HD_*WD*256)    // 802816

// ---------------- pack [Wq|Wk|Wv] into 256x320 + packed bias ----------------
__global__ __launch_bounds__(256) void pack_w(
    const float* __restrict__ Wq, const float* __restrict__ Wk,
    const float* __restrict__ Wv, const float* __restrict__ bq,
    const float* __restrict__ bk, const float* __restrict__ bv,
    float* __restrict__ Wpk, float* __restrict__ pb)
{
    int idx = blockIdx.x * 256 + threadIdx.x;
    if (idx < 256 * 320) {
        int k = idx / 320, n = idx % 320;
        float v;
        if (n < 32)       v = Wq[k * 32 + n];
        else if (n < 64)  v = Wk[k * 32 + (n - 32)];
        else              v = Wv[k * 256 + (n - 64)];
        Wpk[idx] = v;
    }
    if (idx < 320) {
        pb[idx] = (idx < 32) ? bq[idx] : (idx < 64) ? bk[idx - 32] : bv[idx - 64];
    }
}

// ---------------- tiled SGEMM: QKV projection (one batch) ----------------
__global__ __launch_bounds__(256) void sgemm_qkv(
    const float* __restrict__ X, const float* __restrict__ Wpk,
    const float* __restrict__ pb, float* __restrict__ Qb,
    float* __restrict__ Kb, float* __restrict__ Vb)
{
    __shared__ float As[64][20];
    __shared__ float Bs[16][68];
    const int t  = threadIdx.x;
    const int tx = t & 15, ty = t >> 4;
    const int m0 = blockIdx.y * 64;
    const int n0 = blockIdx.x * 64;

    const int ar = t >> 2;
    const int ac = (t & 3) * 4;
    const int br = t >> 4;
    const int bc = (t & 15) * 4;

    float acc[4][4] = {};

    for (int k0 = 0; k0 < 256; k0 += 16) {
        float4 av = *(const float4*)&X[(m0 + ar) * 256 + k0 + ac];
        float4 bv = *(const float4*)&Wpk[(k0 + br) * 320 + n0 + bc];
        __syncthreads();
        *(float4*)&As[ar][ac] = av;
        *(float4*)&Bs[br][bc] = bv;
        __syncthreads();
#pragma unroll
        for (int kk = 0; kk < 16; ++kk) {
            float a0 = As[ty * 4 + 0][kk];
            float a1 = As[ty * 4 + 1][kk];
            float a2 = As[ty * 4 + 2][kk];
            float a3 = As[ty * 4 + 3][kk];
            float4 b = *(float4*)&Bs[kk][tx * 4];
            acc[0][0] += a0 * b.x; acc[0][1] += a0 * b.y; acc[0][2] += a0 * b.z; acc[0][3] += a0 * b.w;
            acc[1][0] += a1 * b.x; acc[1][1] += a1 * b.y; acc[1][2] += a1 * b.z; acc[1][3] += a1 * b.w;
            acc[2][0] += a2 * b.x; acc[2][1] += a2 * b.y; acc[2][2] += a2 * b.z; acc[2][3] += a2 * b.w;
            acc[3][0] += a3 * b.x; acc[3][1] += a3 * b.y; acc[3][2] += a3 * b.z; acc[3][3] += a3 * b.w;
        }
    }

#pragma unroll
    for (int ii = 0; ii < 4; ++ii) {
        int m = m0 + ty * 4 + ii;
#pragma unroll
        for (int jj = 0; jj < 4; ++jj) {
            int n = n0 + tx * 4 + jj;
            float v = acc[ii][jj] + pb[n];
            if (n < 32)       Qb[m * 32 + n] = v;
            else if (n < 64)  Kb[m * 32 + (n - 32)] = v;
            else              Vb[m * 256 + (n - 64)] = v;
        }
    }
}

// ---------------- tiled NATTEN attention (one batch) ----------------
// grid (7,7,8): 8x8 query tile per (head) block; 256 thr = 64 queries x 4.
// Stages the 14x14 K/V halo window + rpb slice in LDS.
__global__ __launch_bounds__(256) void natten_attn_t(
    const float* __restrict__ Qb, const float* __restrict__ Kb,
    const float* __restrict__ Vb, const float* __restrict__ rpb,
    float* __restrict__ Ab)
{
    __shared__ float4 Ks[196];        // 14x14 k-window (lr=4 each)
    __shared__ float4 Vs[8 * 196];    // [d4][pos] channel-quad-major
    __shared__ float  Rs[169];        // rpb slice for this head

    const int tj = blockIdx.x, ti = blockIdx.y, n = blockIdx.z;
    const int t = threadIdx.x;
    const int i0 = ti * 8, j0 = tj * 8;
    const int rs = min(max(i0 - 3, 0), HD_ - 14);   // window row start
    const int cs = min(max(j0 - 3, 0), WD - 14);    // window col start

    const float* kb = Kb + n * (HD_ * WD * LR);
    const float* vb = Vb + n * (HD_ * WD * HDIM);

    if (t < 196) {
        int r = t / 14, c = t % 14;
        Ks[t] = *(const float4*)&kb[(rs + r) * (WD * LR) + (cs + c) * LR];
    }
    if (t < 169) Rs[t] = rpb[n * 169 + t];
    for (int idx = t; idx < 1568; idx += 256) {     // 14*14*8 float4
        int d4 = idx & 7, pos = idx >> 3;
        int r = pos / 14, c = pos % 14;
        Vs[d4 * 196 + pos] = *(const float4*)&vb[(rs + r) * (WD * HDIM) + (cs + c) * HDIM + d4 * 4];
    }
    __syncthreads();

    const int q  = t >> 2, p = t & 3;
    const int qi = q >> 3, qj = q & 7;
    const int i = i0 + qi, j = j0 + qj;
    const int sh = min(max(i - 3, 0), HD_ - KW);
    const int sw = min(max(j - 3, 0), WD - KW);
    const int oh = sh - rs, ow = sw - cs;

    // raw-reshape view: q[n,i,j,l] = Qb[n*12544 + i*224 + j*4 + l]
    float4 qv = *(const float4*)&Qb[n * (HD_ * WD * LR) + i * (WD * LR) + j * LR];
    const float scale = 0.17677669529663687f;       // 32^-0.5

    float s[49];
    float mx = -3.4e38f;
#pragma unroll
    for (int kh = 0; kh < KW; ++kh) {
        int rbase = (sh + kh - i + 6) * 13 + (sw - j + 6);
        int kpos  = (oh + kh) * 14 + ow;
#pragma unroll
        for (int kw = 0; kw < KW; ++kw) {
            float4 kv = Ks[kpos + kw];
            float d = qv.x * kv.x + qv.y * kv.y + qv.z * kv.z + qv.w * kv.w;
            float sc = d * scale + Rs[rbase + kw];
            s[kh * KW + kw] = sc;
            mx = fmaxf(mx, sc);
        }
    }
    float sum = 0.f;
#pragma unroll
    for (int pp = 0; pp < 49; ++pp) { float e = __expf(s[pp] - mx); s[pp] = e; sum += e; }
    float inv = 1.0f / sum;

    float4 a0 = {0.f, 0.f, 0.f, 0.f}, a1 = {0.f, 0.f, 0.f, 0.f};
    const float4* v0 = &Vs[(2 * p) * 196];
    const float4* v1 = &Vs[(2 * p + 1) * 196];
#pragma unroll
    for (int kh = 0; kh < KW; ++kh) {
        int kpos = (oh + kh) * 14 + ow;
#pragma unroll
        for (int kw = 0; kw < KW; ++kw) {
            float w = s[kh * KW + kw] * inv;
            float4 x0 = v0[kpos + kw];
            float4 x1 = v1[kpos + kw];
            a0.x += w * x0.x; a0.y += w * x0.y; a0.z += w * x0.z; a0.w += w * x0.w;
            a1.x += w * x1.x; a1.y += w * x1.y; a1.z += w * x1.z; a1.w += w * x1.w;
        }
    }

    // write to (H,W,C): channel block n*32 + p*8
    float* op = &Ab[(i * WD + j) * CD + n * HDIM + p * 8];
    *(float4*)op = a0;
    *(float4*)(op + 4) = a1;
}

// ---------------- tiled SGEMM: output projection (one batch) ----------------
__global__ __launch_bounds__(256) void sgemm_out(
    const float* __restrict__ A, const float* __restrict__ Wp,
    const float* __restrict__ bp, float* __restrict__ out)
{
    __shared__ float As[64][20];
    __shared__ float Bs[16][68];
    const int t  = threadIdx.x;
    const int tx = t & 15, ty = t >> 4;
    const int m0 = blockIdx.y * 64;
    const int n0 = blockIdx.x * 64;

    const int ar = t >> 2;
    const int ac = (t & 3) * 4;
    const int br = t >> 4;
    const int bc = (t & 15) * 4;

    float acc[4][4] = {};

    for (int k0 = 0; k0 < 256; k0 += 16) {
        float4 av = *(const float4*)&A[(m0 + ar) * 256 + k0 + ac];
        float4 bv = *(const float4*)&Wp[(k0 + br) * 256 + n0 + bc];
        __syncthreads();
        *(float4*)&As[ar][ac] = av;
        *(float4*)&Bs[br][bc] = bv;
        __syncthreads();
#pragma unroll
        for (int kk = 0; kk < 16; ++kk) {
            float a0 = As[ty * 4 + 0][kk];
            float a1 = As[ty * 4 + 1][kk];
            float a2 = As[ty * 4 + 2][kk];
            float a3 = As[ty * 4 + 3][kk];
            float4 b = *(float4*)&Bs[kk][tx * 4];
            acc[0][0] += a0 * b.x; acc[0][1] += a0 * b.y; acc[0][2] += a0 * b.z; acc[0][3] += a0 * b.w;
            acc[1][0] += a1 * b.x; acc[1][1] += a1 * b.y; acc[1][2] += a1 * b.z; acc[1][3] += a1 * b.w;
            acc[2][0] += a2 * b.x; acc[2][1] += a2 * b.y; acc[2][2] += a2 * b.z; acc[2][3] += a2 * b.w;
            acc[3][0] += a3 * b.x; acc[3][1] += a3 * b.y; acc[3][2] += a3 * b.z; acc[3][3] += a3 * b.w;
        }
    }

#pragma unroll
    for (int ii = 0; ii < 4; ++ii) {
        int m = m0 + ty * 4 + ii;
#pragma unroll
        for (int jj = 0; jj < 4; ++jj) {
            int n = n0 + tx * 4 + jj;
            out[m * 256 + n] = acc[ii][jj] + bp[n];
        }
    }
}

extern "C" void kernel_launch(void* const* d_in, const int* in_sizes, int n_in,
                              void* d_out, int out_size, void* d_ws, size_t ws_size,
                              hipStream_t stream) {
    const float* x   = (const float*)d_in[0];
    const float* Wq  = (const float*)d_in[1];
    const float* bq  = (const float*)d_in[2];
    const float* Wk  = (const float*)d_in[3];
    const float* bk  = (const float*)d_in[4];
    const float* Wv  = (const float*)d_in[5];
    const float* bv  = (const float*)d_in[6];
    const float* rpb = (const float*)d_in[7];
    const float* Wp  = (const float*)d_in[8];
    const float* bp  = (const float*)d_in[9];
    float* out = (float*)d_out;

    // workspace layout (floats) — per-batch tiling keeps footprint ~7.55 MB
    float* ws   = (float*)d_ws;
    float* Wpk  = ws;                    // 81920
    float* pb   = Wpk + 81920;           // 320
    float* Qb   = pb + 320;              // 100352
    float* Kb   = Qb + QK_PER_B;         // 100352
    float* Vb   = Kb + QK_PER_B;         // 802816
    float* Ab   = Vb + V_PER_B;          // 802816

    pack_w<<<(256 * 320 + 255) / 256, 256, 0, stream>>>(Wq, Wk, Wv, bq, bk, bv, Wpk, pb);

    for (int b = 0; b < BD; ++b) {
        const float* xb = x + (size_t)b * MB * CD;
        float* outb = out + (size_t)b * MB * CD;

        dim3 gq(320 / 64, MB / 64);
        sgemm_qkv<<<gq, 256, 0, stream>>>(xb, Wpk, pb, Qb, Kb, Vb);

        natten_attn_t<<<dim3(7, 7, 8), 256, 0, stream>>>(Qb, Kb, Vb, rpb, Ab);

        dim3 go(256 / 64, MB / 64);
        sgemm_out<<<go, 256, 0, stream>>>(Ab, Wp, bp, outb);
    }
}

// Round 4
// 169.440 us; speedup vs baseline: 2.4101x; 1.5186x over previous
//
#include <hip/hip_runtime.h>
#include <hip/hip_bf16.h>

// Problem constants (B,H,W,C) = (4,56,56,256), nh=8, K=7, lr=4, hd=32
#define BD 4
#define HD_ 56
#define WD 56
#define CD 256
#define NH 8
#define KW 7
#define LR 4
#define HDIM 32
#define MB (HD_*WD)              // 3136 rows per batch
#define QK_PER_B (HD_*WD*32)     // 100352  (q/k per-batch floats)
#define V_PER_B  (HD_*WD*256)    // 802816

typedef short short8 __attribute__((ext_vector_type(8)));   // 8 bf16 (4 VGPRs)
typedef float floatx4 __attribute__((ext_vector_type(4)));  // MFMA C/D

static __device__ inline ushort f2bf(float f) {
    __hip_bfloat16 h = __float2bfloat16(f);
    return *(ushort*)&h;
}

// ---------------- prep: transposed bf16 weights + packed bias ----------------
// WpkT[n*256+k] (n<320), WpT[n*256+k] (n<256), pb[320]
__global__ __launch_bounds__(256) void prep_w(
    const float* __restrict__ Wq, const float* __restrict__ Wk,
    const float* __restrict__ Wv, const float* __restrict__ bq,
    const float* __restrict__ bk, const float* __restrict__ bv,
    const float* __restrict__ Wp,
    ushort* __restrict__ WpkT, ushort* __restrict__ WpT, float* __restrict__ pb)
{
    int idx = blockIdx.x * 256 + threadIdx.x;
    if (idx < 81920) {
        int n = idx >> 8, k = idx & 255;
        float v;
        if (n < 32)       v = Wq[k * 32 + n];
        else if (n < 64)  v = Wk[k * 32 + (n - 32)];
        else              v = Wv[k * 256 + (n - 64)];
        WpkT[idx] = f2bf(v);
    } else if (idx < 81920 + 65536) {
        int j = idx - 81920;
        int n = j >> 8, k = j & 255;
        WpT[j] = f2bf(Wp[k * 256 + n]);
    } else if (idx < 81920 + 65536 + 320) {
        int n = idx - (81920 + 65536);
        pb[n] = (n < 32) ? bq[n] : (n < 64) ? bk[n - 32] : bv[n - 64];
    }
}

// ---------------- convert x (all batches) to bf16 ----------------
__global__ __launch_bounds__(256) void cvt_x(
    const float* __restrict__ x, ushort* __restrict__ Xb)
{
    int i8 = (blockIdx.x * 256 + threadIdx.x) * 8;   // 401408 threads * 8 = 3211264
    float4 u = *(const float4*)&x[i8];
    float4 v = *(const float4*)&x[i8 + 4];
    union { ushort h[8]; uint4 q; } pk;
    pk.h[0] = f2bf(u.x); pk.h[1] = f2bf(u.y); pk.h[2] = f2bf(u.z); pk.h[3] = f2bf(u.w);
    pk.h[4] = f2bf(v.x); pk.h[5] = f2bf(v.y); pk.h[6] = f2bf(v.z); pk.h[7] = f2bf(v.w);
    *(uint4*)&Xb[i8] = pk.q;
}

// ---------------- MFMA GEMM: QKV projection (one batch) ----------------
// A = Xb[b] bf16 [3136][256], B = WpkT bf16 [320][256] (N-major, K contiguous)
// C[m,n] = A@B^T + pb;  scatter into Q/K (w32 fp32) and V (w256 fp32)
// grid (5, 49), 256 thr = 4 waves; tile 64x64, BK=32
__global__ __launch_bounds__(256) void mfma_qkv(
    const ushort* __restrict__ Ag, const ushort* __restrict__ Bt,
    const float* __restrict__ pb, float* __restrict__ Qb,
    float* __restrict__ Kb, float* __restrict__ Vb)
{
    __shared__ ushort As[64 * 40];   // 64 rows x BK=32 (+8 pad) bf16
    __shared__ ushort Bs[64 * 40];

    const int t = threadIdx.x;
    const int m0 = blockIdx.y * 64;
    const int n0 = blockIdx.x * 64;
    const int r  = t >> 2;           // 0..63 staging row
    const int kq = (t & 3) << 3;     // 0,8,16,24
    const int lane = t & 63, w = t >> 6;
    const int col = lane & 15, quad = lane >> 4;
    const int q8 = quad << 3;

    floatx4 acc[4] = {{0,0,0,0},{0,0,0,0},{0,0,0,0},{0,0,0,0}};

    for (int k0 = 0; k0 < 256; k0 += 32) {
        uint4 av = *(const uint4*)&Ag[(m0 + r) * 256 + k0 + kq];
        uint4 bv = *(const uint4*)&Bt[(n0 + r) * 256 + k0 + kq];
        __syncthreads();
        *(uint4*)&As[r * 40 + kq] = av;
        *(uint4*)&Bs[r * 40 + kq] = bv;
        __syncthreads();
        short8 af = *(short8*)&As[((w << 4) + col) * 40 + q8];
#pragma unroll
        for (int nt = 0; nt < 4; ++nt) {
            short8 bf = *(short8*)&Bs[((nt << 4) + col) * 40 + q8];
            acc[nt] = __builtin_amdgcn_mfma_f32_16x16x32_bf16(af, bf, acc[nt], 0, 0, 0);
        }
    }

#pragma unroll
    for (int nt = 0; nt < 4; ++nt) {
        int gn = n0 + (nt << 4) + col;
        float bias = pb[gn];
#pragma unroll
        for (int rg = 0; rg < 4; ++rg) {
            int m = m0 + (w << 4) + (quad << 2) + rg;
            float v = acc[nt][rg] + bias;
            if (n0 == 0) {
                if (nt < 2) Qb[m * 32 + gn];
                // (branch kept uniform per tile below)
            }
            if (n0 == 0 && nt < 2)      Qb[m * 32 + gn] = v;
            else if (n0 == 0)           Kb[m * 32 + (gn - 32)] = v;
            else                        Vb[m * 256 + (gn - 64)] = v;
        }
    }
}

// ---------------- MFMA GEMM: output projection (one batch) ----------------
// A = Ab bf16 [3136][256], B = WpT bf16 [256][256]; out fp32 + bp
__global__ __launch_bounds__(256) void mfma_out(
    const ushort* __restrict__ Ag, const ushort* __restrict__ Bt,
    const float* __restrict__ bp, float* __restrict__ out)
{
    __shared__ ushort As[64 * 40];
    __shared__ ushort Bs[64 * 40];

    const int t = threadIdx.x;
    const int m0 = blockIdx.y * 64;
    const int n0 = blockIdx.x * 64;
    const int r  = t >> 2;
    const int kq = (t & 3) << 3;
    const int lane = t & 63, w = t >> 6;
    const int col = lane & 15, quad = lane >> 4;
    const int q8 = quad << 3;

    floatx4 acc[4] = {{0,0,0,0},{0,0,0,0},{0,0,0,0},{0,0,0,0}};

    for (int k0 = 0; k0 < 256; k0 += 32) {
        uint4 av = *(const uint4*)&Ag[(m0 + r) * 256 + k0 + kq];
        uint4 bv = *(const uint4*)&Bt[(n0 + r) * 256 + k0 + kq];
        __syncthreads();
        *(uint4*)&As[r * 40 + kq] = av;
        *(uint4*)&Bs[r * 40 + kq] = bv;
        __syncthreads();
        short8 af = *(short8*)&As[((w << 4) + col) * 40 + q8];
#pragma unroll
        for (int nt = 0; nt < 4; ++nt) {
            short8 bf = *(short8*)&Bs[((nt << 4) + col) * 40 + q8];
            acc[nt] = __builtin_amdgcn_mfma_f32_16x16x32_bf16(af, bf, acc[nt], 0, 0, 0);
        }
    }

#pragma unroll
    for (int nt = 0; nt < 4; ++nt) {
        int gn = n0 + (nt << 4) + col;
        float bias = bp[gn];
#pragma unroll
        for (int rg = 0; rg < 4; ++rg) {
            int m = m0 + (w << 4) + (quad << 2) + rg;
            out[m * 256 + gn] = acc[nt][rg] + bias;
        }
    }
}

// ---------------- tiled NATTEN attention (one batch) ----------------
// grid (7,7,8): 8x8 query tile per head; 256 thr = 64 queries x 4.
// Writes att in bf16 (H,W,C) layout for the MFMA output projection.
__global__ __launch_bounds__(256) void natten_attn_t(
    const float* __restrict__ Qb, const float* __restrict__ Kb,
    const float* __restrict__ Vb, const float* __restrict__ rpb,
    ushort* __restrict__ Ab)
{
    __shared__ float4 Ks[196];        // 14x14 k-window (lr=4 each)
    __shared__ float4 Vs[8 * 196];    // [d4][pos] channel-quad-major
    __shared__ float  Rs[169];        // rpb slice for this head

    const int tj = blockIdx.x, ti = blockIdx.y, n = blockIdx.z;
    const int t = threadIdx.x;
    const int i0 = ti * 8, j0 = tj * 8;
    const int rs = min(max(i0 - 3, 0), HD_ - 14);
    const int cs = min(max(j0 - 3, 0), WD - 14);

    const float* kb = Kb + n * (HD_ * WD * LR);
    const float* vb = Vb + n * (HD_ * WD * HDIM);

    if (t < 196) {
        int r = t / 14, c = t % 14;
        Ks[t] = *(const float4*)&kb[(rs + r) * (WD * LR) + (cs + c) * LR];
    }
    if (t < 169) Rs[t] = rpb[n * 169 + t];
    for (int idx = t; idx < 1568; idx += 256) {
        int d4 = idx & 7, pos = idx >> 3;
        int r = pos / 14, c = pos % 14;
        Vs[d4 * 196 + pos] = *(const float4*)&vb[(rs + r) * (WD * HDIM) + (cs + c) * HDIM + d4 * 4];
    }
    __syncthreads();

    const int q  = t >> 2, p = t & 3;
    const int qi = q >> 3, qj = q & 7;
    const int i = i0 + qi, j = j0 + qj;
    const int sh = min(max(i - 3, 0), HD_ - KW);
    const int sw = min(max(j - 3, 0), WD - KW);
    const int oh = sh - rs, ow = sw - cs;

    float4 qv = *(const float4*)&Qb[n * (HD_ * WD * LR) + i * (WD * LR) + j * LR];
    const float scale = 0.17677669529663687f;

    float s[49];
    float mx = -3.4e38f;
#pragma unroll
    for (int kh = 0; kh < KW; ++kh) {
        int rbase = (sh + kh - i + 6) * 13 + (sw - j + 6);
        int kpos  = (oh + kh) * 14 + ow;
#pragma unroll
        for (int kw = 0; kw < KW; ++kw) {
            float4 kv = Ks[kpos + kw];
            float d = qv.x * kv.x + qv.y * kv.y + qv.z * kv.z + qv.w * kv.w;
            float sc = d * scale + Rs[rbase + kw];
            s[kh * KW + kw] = sc;
            mx = fmaxf(mx, sc);
        }
    }
    float sum = 0.f;
#pragma unroll
    for (int pp = 0; pp < 49; ++pp) { float e = __expf(s[pp] - mx); s[pp] = e; sum += e; }
    float inv = 1.0f / sum;

    float4 a0 = {0.f, 0.f, 0.f, 0.f}, a1 = {0.f, 0.f, 0.f, 0.f};
    const float4* v0 = &Vs[(2 * p) * 196];
    const float4* v1 = &Vs[(2 * p + 1) * 196];
#pragma unroll
    for (int kh = 0; kh < KW; ++kh) {
        int kpos = (oh + kh) * 14 + ow;
#pragma unroll
        for (int kw = 0; kw < KW; ++kw) {
            float wt = s[kh * KW + kw] * inv;
            float4 x0 = v0[kpos + kw];
            float4 x1 = v1[kpos + kw];
            a0.x += wt * x0.x; a0.y += wt * x0.y; a0.z += wt * x0.z; a0.w += wt * x0.w;
            a1.x += wt * x1.x; a1.y += wt * x1.y; a1.z += wt * x1.z; a1.w += wt * x1.w;
        }
    }

    // bf16 store: 8 values = 16B, channel block n*32 + p*8
    union { ushort h[8]; uint4 u; } pk;
    pk.h[0] = f2bf(a0.x); pk.h[1] = f2bf(a0.y); pk.h[2] = f2bf(a0.z); pk.h[3] = f2bf(a0.w);
    pk.h[4] = f2bf(a1.x); pk.h[5] = f2bf(a1.y); pk.h[6] = f2bf(a1.z); pk.h[7] = f2bf(a1.w);
    *(uint4*)&Ab[(i * WD + j) * CD + n * HDIM + p * 8] = pk.u;
}

extern "C" void kernel_launch(void* const* d_in, const int* in_sizes, int n_in,
                              void* d_out, int out_size, void* d_ws, size_t ws_size,
                              hipStream_t stream) {
    const float* x   = (const float*)d_in[0];
    const float* Wq  = (const float*)d_in[1];
    const float* bq  = (const float*)d_in[2];
    const float* Wk  = (const float*)d_in[3];
    const float* bk  = (const float*)d_in[4];
    const float* Wv  = (const float*)d_in[5];
    const float* bv  = (const float*)d_in[6];
    const float* rpb = (const float*)d_in[7];
    const float* Wp  = (const float*)d_in[8];
    const float* bp  = (const float*)d_in[9];
    float* out = (float*)d_out;

    // workspace layout — bf16 (ushort) regions first, then fp32; ~12.3 MB
    ushort* WpkT = (ushort*)d_ws;          // 81920
    ushort* WpT  = WpkT + 81920;           // 65536
    ushort* Xb   = WpT + 65536;            // 3211264 (all batches)
    ushort* Ab   = Xb + 3211264;           // 802816  (one batch, bf16)
    float*  pb   = (float*)(Ab + 802816);  // 320
    float*  Qb   = pb + 320;               // 100352
    float*  Kb   = Qb + QK_PER_B;          // 100352
    float*  Vb   = Kb + QK_PER_B;          // 802816

    prep_w<<<(81920 + 65536 + 320 + 255) / 256, 256, 0, stream>>>(
        Wq, Wk, Wv, bq, bk, bv, Wp, WpkT, WpT, pb);
    cvt_x<<<(BD * MB * CD / 8) / 256, 256, 0, stream>>>(x, Xb);

    for (int b = 0; b < BD; ++b) {
        const ushort* xb = Xb + (size_t)b * MB * CD;
        float* outb = out + (size_t)b * MB * CD;

        mfma_qkv<<<dim3(5, 49), 256, 0, stream>>>(xb, WpkT, pb, Qb, Kb, Vb);

        natten_attn_t<<<dim3(7, 7, 8), 256, 0, stream>>>(Qb, Kb, Vb, rpb, Ab);

        mfma_out<<<dim3(4, 49), 256, 0, stream>>>(Ab, WpT, bp, outb);
    }
}

// Round 5
// 131.278 us; speedup vs baseline: 3.1107x; 1.2907x over previous
//
#include <hip/hip_runtime.h>
#include <hip/hip_bf16.h>

// Problem constants (B,H,W,C) = (4,56,56,256), nh=8, K=7, lr=4, hd=32
#define BD 4
#define HD_ 56
#define WD 56
#define CD 256
#define NH 8
#define KW 7
#define LR 4
#define HDIM 32
#define MB (HD_*WD)              // 3136 rows per batch
#define NROWS (BD*MB)            // 12544 total rows
#define QK_PER_B (HD_*WD*32)     // 100352  (q/k per-batch floats)
#define V_PER_B  (HD_*WD*256)    // 802816

typedef short short8 __attribute__((ext_vector_type(8)));   // 8 bf16 (4 VGPRs)
typedef float floatx4 __attribute__((ext_vector_type(4)));  // MFMA C/D

static __device__ inline ushort f2bf(float f) {
    __hip_bfloat16 h = __float2bfloat16(f);
    return *(ushort*)&h;
}

// ---------------- prep: transposed bf16 weights + packed bias ----------------
// WpkT[n*256+k] (n<320), WpT[n*256+k] (n<256), pb[320]
__global__ __launch_bounds__(256) void prep_w(
    const float* __restrict__ Wq, const float* __restrict__ Wk,
    const float* __restrict__ Wv, const float* __restrict__ bq,
    const float* __restrict__ bk, const float* __restrict__ bv,
    const float* __restrict__ Wp,
    ushort* __restrict__ WpkT, ushort* __restrict__ WpT, float* __restrict__ pb)
{
    int idx = blockIdx.x * 256 + threadIdx.x;
    if (idx < 81920) {
        int n = idx >> 8, k = idx & 255;
        float v;
        if (n < 32)       v = Wq[k * 32 + n];
        else if (n < 64)  v = Wk[k * 32 + (n - 32)];
        else              v = Wv[k * 256 + (n - 64)];
        WpkT[idx] = f2bf(v);
    } else if (idx < 81920 + 65536) {
        int j = idx - 81920;
        int n = j >> 8, k = j & 255;
        WpT[j] = f2bf(Wp[k * 256 + n]);
    } else if (idx < 81920 + 65536 + 320) {
        int n = idx - (81920 + 65536);
        pb[n] = (n < 32) ? bq[n] : (n < 64) ? bk[n - 32] : bv[n - 64];
    }
}

// ---------------- convert x (all batches) to bf16 ----------------
__global__ __launch_bounds__(256) void cvt_x(
    const float* __restrict__ x, ushort* __restrict__ Xb)
{
    int i8 = (blockIdx.x * 256 + threadIdx.x) * 8;
    float4 u = *(const float4*)&x[i8];
    float4 v = *(const float4*)&x[i8 + 4];
    union { ushort h[8]; uint4 q; } pk;
    pk.h[0] = f2bf(u.x); pk.h[1] = f2bf(u.y); pk.h[2] = f2bf(u.z); pk.h[3] = f2bf(u.w);
    pk.h[4] = f2bf(v.x); pk.h[5] = f2bf(v.y); pk.h[6] = f2bf(v.z); pk.h[7] = f2bf(v.w);
    *(uint4*)&Xb[i8] = pk.q;
}

// ---------------- MFMA GEMM: QKV projection (ALL batches) ----------------
// A = Xb bf16 [12544][256], B = WpkT bf16 [320][256] (N-major, K contiguous)
// C[m,n] = A@B^T + pb;  scatter into Q/K (w32 fp32) and V (w256 fp32)
// grid (5, 196), 256 thr = 4 waves; tile 64x64, BK=32
__global__ __launch_bounds__(256) void mfma_qkv(
    const ushort* __restrict__ Ag, const ushort* __restrict__ Bt,
    const float* __restrict__ pb, float* __restrict__ Qb,
    float* __restrict__ Kb, float* __restrict__ Vb)
{
    __shared__ ushort As[64 * 40];   // 64 rows x BK=32 (+8 pad) bf16
    __shared__ ushort Bs[64 * 40];

    const int t = threadIdx.x;
    const int m0 = blockIdx.y * 64;
    const int n0 = blockIdx.x * 64;
    const int r  = t >> 2;           // 0..63 staging row
    const int kq = (t & 3) << 3;     // 0,8,16,24
    const int lane = t & 63, w = t >> 6;
    const int col = lane & 15, quad = lane >> 4;
    const int q8 = quad << 3;

    floatx4 acc[4] = {{0,0,0,0},{0,0,0,0},{0,0,0,0},{0,0,0,0}};

    for (int k0 = 0; k0 < 256; k0 += 32) {
        uint4 av = *(const uint4*)&Ag[(m0 + r) * 256 + k0 + kq];
        uint4 bv = *(const uint4*)&Bt[(n0 + r) * 256 + k0 + kq];
        __syncthreads();
        *(uint4*)&As[r * 40 + kq] = av;
        *(uint4*)&Bs[r * 40 + kq] = bv;
        __syncthreads();
        short8 af = *(short8*)&As[((w << 4) + col) * 40 + q8];
#pragma unroll
        for (int nt = 0; nt < 4; ++nt) {
            short8 bf = *(short8*)&Bs[((nt << 4) + col) * 40 + q8];
            acc[nt] = __builtin_amdgcn_mfma_f32_16x16x32_bf16(af, bf, acc[nt], 0, 0, 0);
        }
    }

#pragma unroll
    for (int nt = 0; nt < 4; ++nt) {
        int gn = n0 + (nt << 4) + col;
        float bias = pb[gn];
#pragma unroll
        for (int rg = 0; rg < 4; ++rg) {
            int m = m0 + (w << 4) + (quad << 2) + rg;
            float v = acc[nt][rg] + bias;
            if (n0 == 0 && nt < 2)      Qb[m * 32 + gn] = v;
            else if (n0 == 0)           Kb[m * 32 + (gn - 32)] = v;
            else                        Vb[m * 256 + (gn - 64)] = v;
        }
    }
}

// ---------------- MFMA GEMM: output projection (ALL batches) ----------------
// A = Ab bf16 [12544][256], B = WpT bf16 [256][256]; out fp32 + bp
__global__ __launch_bounds__(256) void mfma_out(
    const ushort* __restrict__ Ag, const ushort* __restrict__ Bt,
    const float* __restrict__ bp, float* __restrict__ out)
{
    __shared__ ushort As[64 * 40];
    __shared__ ushort Bs[64 * 40];

    const int t = threadIdx.x;
    const int m0 = blockIdx.y * 64;
    const int n0 = blockIdx.x * 64;
    const int r  = t >> 2;
    const int kq = (t & 3) << 3;
    const int lane = t & 63, w = t >> 6;
    const int col = lane & 15, quad = lane >> 4;
    const int q8 = quad << 3;

    floatx4 acc[4] = {{0,0,0,0},{0,0,0,0},{0,0,0,0},{0,0,0,0}};

    for (int k0 = 0; k0 < 256; k0 += 32) {
        uint4 av = *(const uint4*)&Ag[(m0 + r) * 256 + k0 + kq];
        uint4 bv = *(const uint4*)&Bt[(n0 + r) * 256 + k0 + kq];
        __syncthreads();
        *(uint4*)&As[r * 40 + kq] = av;
        *(uint4*)&Bs[r * 40 + kq] = bv;
        __syncthreads();
        short8 af = *(short8*)&As[((w << 4) + col) * 40 + q8];
#pragma unroll
        for (int nt = 0; nt < 4; ++nt) {
            short8 bf = *(short8*)&Bs[((nt << 4) + col) * 40 + q8];
            acc[nt] = __builtin_amdgcn_mfma_f32_16x16x32_bf16(af, bf, acc[nt], 0, 0, 0);
        }
    }

#pragma unroll
    for (int nt = 0; nt < 4; ++nt) {
        int gn = n0 + (nt << 4) + col;
        float bias = bp[gn];
#pragma unroll
        for (int rg = 0; rg < 4; ++rg) {
            int m = m0 + (w << 4) + (quad << 2) + rg;
            out[m * 256 + gn] = acc[nt][rg] + bias;
        }
    }
}

// ---------------- tiled NATTEN attention (ALL batches) ----------------
// grid (7,7,32): z = b*8+n; 8x8 query tile; 256 thr = 64 queries x 4.
// Writes att in bf16 (B,H,W,C) layout for the MFMA output projection.
__global__ __launch_bounds__(256) void natten_attn_t(
    const float* __restrict__ Qb, const float* __restrict__ Kb,
    const float* __restrict__ Vb, const float* __restrict__ rpb,
    ushort* __restrict__ Ab)
{
    __shared__ float4 Ks[196];        // 14x14 k-window (lr=4 each)
    __shared__ float4 Vs[8 * 196];    // [d4][pos] channel-quad-major
    __shared__ float  Rs[169];        // rpb slice for this head

    const int tj = blockIdx.x, ti = blockIdx.y;
    const int n = blockIdx.z & 7, b = blockIdx.z >> 3;
    const int t = threadIdx.x;
    const int i0 = ti * 8, j0 = tj * 8;
    const int rs = min(max(i0 - 3, 0), HD_ - 14);
    const int cs = min(max(j0 - 3, 0), WD - 14);

    // raw-reshape views:
    // q/k[b,n,i,j,l] = Q[b*100352 + n*12544 + i*224 + j*4 + l]
    // v[b,n,i,j,d]   = V[b*802816 + n*100352 + i*1792 + j*32 + d]
    const float* kb = Kb + b * QK_PER_B + n * (HD_ * WD * LR);
    const float* vb = Vb + b * V_PER_B + n * (HD_ * WD * HDIM);

    if (t < 196) {
        int r = t / 14, c = t % 14;
        Ks[t] = *(const float4*)&kb[(rs + r) * (WD * LR) + (cs + c) * LR];
    }
    if (t < 169) Rs[t] = rpb[n * 169 + t];
    for (int idx = t; idx < 1568; idx += 256) {
        int d4 = idx & 7, pos = idx >> 3;
        int r = pos / 14, c = pos % 14;
        Vs[d4 * 196 + pos] = *(const float4*)&vb[(rs + r) * (WD * HDIM) + (cs + c) * HDIM + d4 * 4];
    }
    __syncthreads();

    const int q  = t >> 2, p = t & 3;
    const int qi = q >> 3, qj = q & 7;
    const int i = i0 + qi, j = j0 + qj;
    const int sh = min(max(i - 3, 0), HD_ - KW);
    const int sw = min(max(j - 3, 0), WD - KW);
    const int oh = sh - rs, ow = sw - cs;

    float4 qv = *(const float4*)&Qb[b * QK_PER_B + n * (HD_ * WD * LR) + i * (WD * LR) + j * LR];
    const float scale = 0.17677669529663687f;

    float s[49];
    float mx = -3.4e38f;
#pragma unroll
    for (int kh = 0; kh < KW; ++kh) {
        int rbase = (sh + kh - i + 6) * 13 + (sw - j + 6);
        int kpos  = (oh + kh) * 14 + ow;
#pragma unroll
        for (int kw = 0; kw < KW; ++kw) {
            float4 kv = Ks[kpos + kw];
            float d = qv.x * kv.x + qv.y * kv.y + qv.z * kv.z + qv.w * kv.w;
            float sc = d * scale + Rs[rbase + kw];
            s[kh * KW + kw] = sc;
            mx = fmaxf(mx, sc);
        }
    }
    float sum = 0.f;
#pragma unroll
    for (int pp = 0; pp < 49; ++pp) { float e = __expf(s[pp] - mx); s[pp] = e; sum += e; }
    float inv = 1.0f / sum;

    float4 a0 = {0.f, 0.f, 0.f, 0.f}, a1 = {0.f, 0.f, 0.f, 0.f};
    const float4* v0 = &Vs[(2 * p) * 196];
    const float4* v1 = &Vs[(2 * p + 1) * 196];
#pragma unroll
    for (int kh = 0; kh < KW; ++kh) {
        int kpos = (oh + kh) * 14 + ow;
#pragma unroll
        for (int kw = 0; kw < KW; ++kw) {
            float wt = s[kh * KW + kw] * inv;
            float4 x0 = v0[kpos + kw];
            float4 x1 = v1[kpos + kw];
            a0.x += wt * x0.x; a0.y += wt * x0.y; a0.z += wt * x0.z; a0.w += wt * x0.w;
            a1.x += wt * x1.x; a1.y += wt * x1.y; a1.z += wt * x1.z; a1.w += wt * x1.w;
        }
    }

    // bf16 store: 8 values = 16B, channel block n*32 + p*8
    union { ushort h[8]; uint4 u; } pk;
    pk.h[0] = f2bf(a0.x); pk.h[1] = f2bf(a0.y); pk.h[2] = f2bf(a0.z); pk.h[3] = f2bf(a0.w);
    pk.h[4] = f2bf(a1.x); pk.h[5] = f2bf(a1.y); pk.h[6] = f2bf(a1.z); pk.h[7] = f2bf(a1.w);
    *(uint4*)&Ab[(((b * HD_ + i) * WD + j)) * CD + n * HDIM + p * 8] = pk.u;
}

extern "C" void kernel_launch(void* const* d_in, const int* in_sizes, int n_in,
                              void* d_out, int out_size, void* d_ws, size_t ws_size,
                              hipStream_t stream) {
    const float* x   = (const float*)d_in[0];
    const float* Wq  = (const float*)d_in[1];
    const float* bq  = (const float*)d_in[2];
    const float* Wk  = (const float*)d_in[3];
    const float* bk  = (const float*)d_in[4];
    const float* Wv  = (const float*)d_in[5];
    const float* bv  = (const float*)d_in[6];
    const float* rpb = (const float*)d_in[7];
    const float* Wp  = (const float*)d_in[8];
    const float* bp  = (const float*)d_in[9];
    float* out = (float*)d_out;

    // workspace layout — full-batch; ~29.2 MB of the 256 MiB ws
    ushort* WpkT = (ushort*)d_ws;          // 81920
    ushort* WpT  = WpkT + 81920;           // 65536
    ushort* Xb   = WpT + 65536;            // 3211264 (all batches)
    ushort* Ab   = Xb + 3211264;           // 3211264 (all batches, bf16)
    float*  pb   = (float*)(Ab + 3211264); // 320
    float*  Qb   = pb + 320;               // 401408
    float*  Kb   = Qb + BD * QK_PER_B;     // 401408
    float*  Vb   = Kb + BD * QK_PER_B;     // 3211264

    prep_w<<<(81920 + 65536 + 320 + 255) / 256, 256, 0, stream>>>(
        Wq, Wk, Wv, bq, bk, bv, Wp, WpkT, WpT, pb);
    cvt_x<<<(NROWS * CD / 8) / 256, 256, 0, stream>>>(x, Xb);

    mfma_qkv<<<dim3(5, NROWS / 64), 256, 0, stream>>>(Xb, WpkT, pb, Qb, Kb, Vb);

    natten_attn_t<<<dim3(7, 7, 32), 256, 0, stream>>>(Qb, Kb, Vb, rpb, Ab);

    mfma_out<<<dim3(4, NROWS / 64), 256, 0, stream>>>(Ab, WpT, bp, out);
}